// Round 13
// baseline (41.182 us; speedup 1.0000x reference)
//
#include <hip/hip_runtime.h>
#include <stdint.h>

// AeTransformer_44839458570443: 3-NN inverse-distance interpolation + (tanh+1)/2.
// xyz1: [B,3,N] fp32, xyz2: [B,3,S] fp32, points2: [B,1,S] fp32 -> out [B,N] fp32.
//
// Selection bit-matches the reference fp32 expanded distance
//   d = (-2*((x*x'+y*y')+z*z') + ||q||^2) + ||p||^2   (fp32, no FMA)
// ordered by (d, index).
//
// Round 13: DUAL-PIPE phase A. R6 proved the LDS-broadcast scan sustains the
// full table at ~39us/CU; R11/R12 proved the SMEM (s_load/K$) scan does the
// same ~35-39us. They use DIFFERENT hardware pipes (LDS vs K$) -- this round
// runs them CONCURRENTLY on different waves of each pair:
//   wave h=0: groups 0-31 from a 4KB LDS tile (broadcast ds_read_b128)
//   wave h=1: groups 32-63 via s_load (K$, scalar path; laundered uniform)
// Each pipe sees HALF its standalone demand (~20us LDS, ~18us K$) and they
// overlap, with VALU (~20us) shared. MERGE: 5 group-keys per query through
// LDS + one barrier + INS5 (halves disjoint, keys unique -> min-5 of union ==
// merge of per-half min-5s). h=1 retires after the barrier; h=0 runs phase C.
// PHASE A (proxy): per group of 8, 3-FMA distances + min tree -> group min;
//   keep 5 best (group-min | gid) keys. Lemma: at most 3 groups can have
//   min <= d3 -> top-3 lives in best-3 groups; 5 kept for proxy margin.
// PHASE C (global/L1 divergent gathers; R8-R12-proven, 0 bank conflicts):
//   FMA-proxy rescan of the 40 survivors, 9-bit-quantized 6-slot screen,
//   exact replicated ref_d on 6, (d,idx) sort, replicated fp32 weight chain.
static constexpr int B = 4;
static constexpr int N = 65536;
static constexpr int S = 512;

__global__ __launch_bounds__(256) void prep_kernel(const float* __restrict__ xyz2,
                                                   float4* __restrict__ ws) {
    int t = blockIdx.x * 256 + threadIdx.x;
    if (t >= B * S) return;
    int b = t >> 9, s = t & 511;
    const float* p = xyz2 + (size_t)b * 3 * S;
    float x = p[s], y = p[s + S], z = p[s + 2 * S];
    float c = __fadd_rn(__fadd_rn(__fmul_rn(x, x), __fmul_rn(y, y)), __fmul_rn(z, z));
    ws[t] = make_float4(x, y, z, c);
}

// Reference-replicated fp32 distance (numpy order, no contraction)
__device__ __forceinline__ float ref_d(float x1, float y1, float z1, float ssrc, float4 p) {
    float dot = __fadd_rn(__fadd_rn(__fmul_rn(x1, p.x), __fmul_rn(y1, p.y)),
                          __fmul_rn(z1, p.z));
    float t = __fmul_rn(dot, -2.0f);
    return __fadd_rn(__fadd_rn(t, ssrc), p.w);
}

#define CAS(da_, ia_, db_, ib_)                                     \
    {                                                               \
        bool sw_ = (db_ < da_) || ((db_ == da_) && (ib_ < ia_));    \
        float tda_ = sw_ ? db_ : da_;                               \
        int tia_ = sw_ ? ib_ : ia_;                                 \
        db_ = sw_ ? da_ : db_;                                      \
        ib_ = sw_ ? ia_ : ib_;                                      \
        da_ = tda_;                                                 \
        ia_ = tia_;                                                 \
    }

#define INS5(k)                                                     \
    {                                                               \
        float t4 = __builtin_amdgcn_fmed3f(g3, (k), g4);            \
        float t3 = __builtin_amdgcn_fmed3f(g2, (k), g3);            \
        float t2 = __builtin_amdgcn_fmed3f(g1, (k), g2);            \
        float t1 = __builtin_amdgcn_fmed3f(g0, (k), g1);            \
        g0 = fminf(g0, (k));                                        \
        g1 = t1; g2 = t2; g3 = t3; g4 = t4;                         \
    }

#define INS6(k)                                                     \
    {                                                               \
        float t5 = __builtin_amdgcn_fmed3f(m4, (k), m5);            \
        float t4 = __builtin_amdgcn_fmed3f(m3, (k), m4);            \
        float t3 = __builtin_amdgcn_fmed3f(m2, (k), m3);            \
        float t2 = __builtin_amdgcn_fmed3f(m1, (k), m2);            \
        float t1 = __builtin_amdgcn_fmed3f(m0, (k), m1);            \
        m0 = fminf(m0, (k));                                        \
        m1 = t1; m2 = t2; m3 = t3; m4 = t4; m5 = t5;                \
    }

// Phase-A group body for 8 candidates already in p[] (VGPRs)
#define PROC_GROUP(p, gid)                                                   \
    {                                                                        \
        float e[8];                                                          \
        _Pragma("unroll") for (int j = 0; j < 8; ++j)                        \
            e[j] = fmaf(nx2, p[j].x,                                         \
                        fmaf(ny2, p[j].y, fmaf(nz2, p[j].z, p[j].w)));       \
        float mA = fminf(fminf(e[0], e[1]), e[2]);                           \
        float mB = fminf(fminf(e[3], e[4]), e[5]);                           \
        float mC = fminf(fminf(mA, mB), e[6]);                               \
        float gm = fminf(mC, e[7]);                                          \
        float gkey = __uint_as_float(                                        \
            (__float_as_uint(gm + c) & 0xFFFFFFC0u) | (uint32_t)(gid));      \
        INS5(gkey);                                                          \
    }

__global__ __launch_bounds__(256, 8) void knn3_kernel(const float* __restrict__ xyz1,
                                                      const float* __restrict__ points2,
                                                      const float4* __restrict__ ws,
                                                      float* __restrict__ out) {
    __shared__ float4 tile[256];       // 4 KB: groups 0-31 (LDS-pipe half)
    __shared__ float keys_sh[5][256];  // 5 KB group-key exchange
    const int tid = threadIdx.x;
    const int lane = tid & 63;
    const int pr = tid >> 7;           // wave-pair id within block (0,1)
    const int b = blockIdx.x >> 9;     // 512 blocks per batch
    const int n = ((blockIdx.x & 511) << 7) + (pr << 6) + lane;

    // Wave-uniform values laundered into SGPRs (scalar path for h=1 scan)
    const int b_u = __builtin_amdgcn_readfirstlane(b);
    const int h_u = __builtin_amdgcn_readfirstlane((tid >> 6) & 1);
    const float4* __restrict__ wtab = ws + (size_t)b_u * S;  // uniform scan
    const float4* __restrict__ wvec = ws + (size_t)b * S;    // divergent gathers

    tile[tid] = wvec[tid];  // stage groups 0-31 (first 256 candidates)
    __syncthreads();

    const float* q = xyz1 + (size_t)b * 3 * N;
    float x1 = q[n], y1 = q[n + N], z1 = q[n + 2 * N];
    float ssrc = __fadd_rn(__fadd_rn(__fmul_rn(x1, x1), __fmul_rn(y1, y1)),
                           __fmul_rn(z1, z1));
    // screen-only constants (proxy zone; phase C refine is exact)
    float c = ssrc + 0.25f;  // bias keeps packed keys > 0
    float nx2 = -2.0f * x1, ny2 = -2.0f * y1, nz2 = -2.0f * z1;

    // ---- Phase A: dual-pipe; each wave scans its 32 groups ----
    float g0 = 3.0e38f, g1 = 3.0e38f, g2 = 3.0e38f, g3 = 3.0e38f, g4 = 3.0e38f;
    if (h_u == 0) {
        // LDS half: groups 0-31, broadcast ds_read_b128
#pragma unroll 2
        for (int g = 0; g < 32; ++g) {
            float4 p[8];
#pragma unroll
            for (int j = 0; j < 8; ++j) p[j] = tile[g * 8 + j];
            PROC_GROUP(p, g);
        }
    } else {
        // SMEM half: groups 32-63 via s_load (K$, scalar pipe)
#pragma unroll 2
        for (int g = 32; g < 64; ++g) {
            float4 p[8];
#pragma unroll
            for (int j = 0; j < 8; ++j) p[j] = wtab[g * 8 + j];
            PROC_GROUP(p, g);
        }
    }

    // ---- publish keys; merge within wave pair ----
    keys_sh[0][tid] = g0;
    keys_sh[1][tid] = g1;
    keys_sh[2][tid] = g2;
    keys_sh[3][tid] = g3;
    keys_sh[4][tid] = g4;
    __syncthreads();
    if (h_u) return;  // SMEM-half waves done (R4/R12-proven pattern)

    {
        const int ptid = tid ^ 64;  // partner wave, same lane
        float pk0 = keys_sh[0][ptid], pk1 = keys_sh[1][ptid],
              pk2 = keys_sh[2][ptid], pk3 = keys_sh[3][ptid],
              pk4 = keys_sh[4][ptid];
        INS5(pk0); INS5(pk1); INS5(pk2); INS5(pk3); INS5(pk4);
    }

    // ---- Phase C: global/L1 divergent gathers; proxy 6-slot screen ----
    float m0 = 3.0e38f, m1 = 3.0e38f, m2 = 3.0e38f,
          m3 = 3.0e38f, m4 = 3.0e38f, m5 = 3.0e38f;
    float gkeys[5] = {g0, g1, g2, g3, g4};
#pragma unroll
    for (int t = 0; t < 5; ++t) {
        int gbase = (int)(__float_as_uint(gkeys[t]) & 63u) << 3;
#pragma unroll
        for (int j = 0; j < 8; ++j) {
            float4 p = wvec[gbase + j];  // divergent gather, L1-resident
            float e2 = fmaf(nx2, p.x,
                            fmaf(ny2, p.y, fmaf(nz2, p.z, p.w + c)));
            float k = __uint_as_float((__float_as_uint(e2) & 0xFFFFFE00u) |
                                      (uint32_t)(gbase + j));
            INS6(k);
        }
    }

    // ---- Refine: re-score 6 survivors exactly, sort by (d, idx) ----
    int gi[6];
    float dd[6];
    gi[0] = (int)(__float_as_uint(m0) & 511u);
    gi[1] = (int)(__float_as_uint(m1) & 511u);
    gi[2] = (int)(__float_as_uint(m2) & 511u);
    gi[3] = (int)(__float_as_uint(m3) & 511u);
    gi[4] = (int)(__float_as_uint(m4) & 511u);
    gi[5] = (int)(__float_as_uint(m5) & 511u);
#pragma unroll
    for (int j = 0; j < 6; ++j) dd[j] = ref_d(x1, y1, z1, ssrc, wvec[gi[j]]);

#pragma unroll
    for (int pp = 0; pp < 3; ++pp)
#pragma unroll
        for (int i = 4; i >= pp; --i) CAS(dd[i], gi[i], dd[i + 1], gi[i + 1]);

    // Replicate reference weight/interp chain in fp32, nearest-first order
    const float EPS32 = 1e-8f;
    float r0 = __fdiv_rn(1.0f, __fadd_rn(dd[0], EPS32));
    float r1 = __fdiv_rn(1.0f, __fadd_rn(dd[1], EPS32));
    float r2 = __fdiv_rn(1.0f, __fadd_rn(dd[2], EPS32));
    float rs = __fadd_rn(__fadd_rn(r0, r1), r2);
    float w0 = __fdiv_rn(r0, rs);
    float w1 = __fdiv_rn(r1, rs);
    float w2 = __fdiv_rn(r2, rs);
    const float* f = points2 + (size_t)b * S;  // D = 1
    float interp = __fadd_rn(__fadd_rn(__fmul_rn(f[gi[0]], w0), __fmul_rn(f[gi[1]], w1)),
                             __fmul_rn(f[gi[2]], w2));
    float t = tanhf(interp);
    out[((size_t)b << 16) | (uint32_t)n] = __fmul_rn(__fadd_rn(t, 1.0f), 0.5f);
}

extern "C" void kernel_launch(void* const* d_in, const int* in_sizes, int n_in,
                              void* d_out, int out_size, void* d_ws, size_t ws_size,
                              hipStream_t stream) {
    const float* xyz1 = (const float*)d_in[0];
    const float* xyz2 = (const float*)d_in[1];
    const float* points2 = (const float*)d_in[2];
    float* out = (float*)d_out;
    float4* ws = (float4*)d_ws;  // B*S*16 = 32 KB

    prep_kernel<<<(B * S + 255) / 256, 256, 0, stream>>>(xyz2, ws);
    // 2048 blocks x 256 threads: wave pairs share 64 queries; wave 0 scans
    // groups 0-31 via LDS, wave 1 scans groups 32-63 via s_load (K$)
    knn3_kernel<<<(B * N) / 128, 256, 0, stream>>>(xyz1, points2, ws, out);
}

// Round 14
// 38.605 us; speedup vs baseline: 1.0668x; 1.0668x over previous
//
#include <hip/hip_runtime.h>
#include <stdint.h>

// AeTransformer_44839458570443: 3-NN inverse-distance interpolation + (tanh+1)/2.
// xyz1: [B,3,N] fp32, xyz2: [B,3,S] fp32, points2: [B,1,S] fp32 -> out [B,N] fp32.
//
// Selection bit-matches the reference fp32 expanded distance
//   d = (-2*((x*x'+y*y')+z*z') + ||q||^2) + ||p||^2   (fp32, no FMA)
// ordered by (d, index).
//
// Round 14: Q=2 x SPLIT-2. Invariant discovered R6-R13: with 1 query/lane,
// candidate-split leaves total broadcast traffic at 2.1M reads (~41us LDS).
// Query-blocking Q=2 HALVES traffic (each ds_read_b128 serves 2 queries);
// split-2 across the wave pair restores 4096 waves (4/SIMD) for latency
// hiding. VGPR stays ~100 < 128 cap -> no spills (R7's failure). No dead
// waves: after the merge, wave h of each pair runs phase C for query-slot h.
// PHASE A (proxy): per group of 8 (own half, 32 groups), 3-FMA distances +
//   min tree -> group min; keep 5 best (group-min | gid) keys PER QUERY.
//   Lemma: at most 3 groups can have min <= d3; 5 kept for proxy margin.
// MERGE: per-query 5-key lists exchanged via LDS (disjoint halves, unique
//   gid bits -> min-5 of union == INS5-merge of per-half min-5s).
// PHASE C (global/L1 divergent gathers; R8-R13-proven, 0 bank conflicts):
//   FMA-proxy rescan of 40 survivors, 9-bit-quantized 6-slot screen,
//   exact replicated ref_d on 6, (d,idx) sort, replicated fp32 weight chain.
static constexpr int B = 4;
static constexpr int N = 65536;
static constexpr int S = 512;

__global__ __launch_bounds__(256) void prep_kernel(const float* __restrict__ xyz2,
                                                   float4* __restrict__ ws) {
    int t = blockIdx.x * 256 + threadIdx.x;
    if (t >= B * S) return;
    int b = t >> 9, s = t & 511;
    const float* p = xyz2 + (size_t)b * 3 * S;
    float x = p[s], y = p[s + S], z = p[s + 2 * S];
    float c = __fadd_rn(__fadd_rn(__fmul_rn(x, x), __fmul_rn(y, y)), __fmul_rn(z, z));
    ws[t] = make_float4(x, y, z, c);
}

// Reference-replicated fp32 distance (numpy order, no contraction)
__device__ __forceinline__ float ref_d(float x1, float y1, float z1, float ssrc, float4 p) {
    float dot = __fadd_rn(__fadd_rn(__fmul_rn(x1, p.x), __fmul_rn(y1, p.y)),
                          __fmul_rn(z1, p.z));
    float t = __fmul_rn(dot, -2.0f);
    return __fadd_rn(__fadd_rn(t, ssrc), p.w);
}

#define CAS(da_, ia_, db_, ib_)                                     \
    {                                                               \
        bool sw_ = (db_ < da_) || ((db_ == da_) && (ib_ < ia_));    \
        float tda_ = sw_ ? db_ : da_;                               \
        int tia_ = sw_ ? ib_ : ia_;                                 \
        db_ = sw_ ? da_ : db_;                                      \
        ib_ = sw_ ? ia_ : ib_;                                      \
        da_ = tda_;                                                 \
        ia_ = tia_;                                                 \
    }

// sorted insert into ascending 5-list (named slots)
#define INS5L(A0, A1, A2, A3, A4, k)                                \
    {                                                               \
        float t4 = __builtin_amdgcn_fmed3f(A3, (k), A4);            \
        float t3 = __builtin_amdgcn_fmed3f(A2, (k), A3);            \
        float t2 = __builtin_amdgcn_fmed3f(A1, (k), A2);            \
        float t1 = __builtin_amdgcn_fmed3f(A0, (k), A1);            \
        A0 = fminf(A0, (k));                                        \
        A1 = t1; A2 = t2; A3 = t3; A4 = t4;                         \
    }

#define INS6(k)                                                     \
    {                                                               \
        float t5 = __builtin_amdgcn_fmed3f(m4, (k), m5);            \
        float t4 = __builtin_amdgcn_fmed3f(m3, (k), m4);            \
        float t3 = __builtin_amdgcn_fmed3f(m2, (k), m3);            \
        float t2 = __builtin_amdgcn_fmed3f(m1, (k), m2);            \
        float t1 = __builtin_amdgcn_fmed3f(m0, (k), m1);            \
        m0 = fminf(m0, (k));                                        \
        m1 = t1; m2 = t2; m3 = t3; m4 = t4; m5 = t5;                \
    }

// Phase-A body for one query on a group of 8 already in p[]
#define PROC_GQ(NX, NY, NZ, CC, A0, A1, A2, A3, A4, gid)                      \
    {                                                                         \
        float e[8];                                                           \
        _Pragma("unroll") for (int j = 0; j < 8; ++j)                         \
            e[j] = fmaf(NX, p[j].x,                                           \
                        fmaf(NY, p[j].y, fmaf(NZ, p[j].z, p[j].w)));          \
        float mA = fminf(fminf(e[0], e[1]), e[2]);                            \
        float mB = fminf(fminf(e[3], e[4]), e[5]);                            \
        float mC = fminf(fminf(mA, mB), e[6]);                                \
        float gm = fminf(mC, e[7]);                                           \
        float gkey = __uint_as_float(                                         \
            (__float_as_uint(gm + CC) & 0xFFFFFFC0u) | (uint32_t)(gid));      \
        INS5L(A0, A1, A2, A3, A4, gkey);                                      \
    }

// Phase C + refine + epilogue for one query (all names passed explicitly)
#define PHASE_C(NX, NY, NZ, CC, X1, Y1, Z1, SS, K0, K1, K2, K3, K4, NOUT)     \
    {                                                                         \
        float m0 = 3.0e38f, m1 = 3.0e38f, m2 = 3.0e38f,                       \
              m3 = 3.0e38f, m4 = 3.0e38f, m5 = 3.0e38f;                       \
        float gkeys[5] = {K0, K1, K2, K3, K4};                                \
        _Pragma("unroll") for (int t = 0; t < 5; ++t) {                       \
            int gbase = (int)(__float_as_uint(gkeys[t]) & 63u) << 3;          \
            _Pragma("unroll") for (int j = 0; j < 8; ++j) {                   \
                float4 p = wvec[gbase + j]; /* divergent gather, L1 */        \
                float e2 = fmaf(NX, p.x,                                      \
                                fmaf(NY, p.y, fmaf(NZ, p.z, p.w + CC)));      \
                float k = __uint_as_float((__float_as_uint(e2) & 0xFFFFFE00u) \
                                          | (uint32_t)(gbase + j));           \
                INS6(k);                                                      \
            }                                                                 \
        }                                                                     \
        int gi[6];                                                            \
        float dd[6];                                                          \
        gi[0] = (int)(__float_as_uint(m0) & 511u);                            \
        gi[1] = (int)(__float_as_uint(m1) & 511u);                            \
        gi[2] = (int)(__float_as_uint(m2) & 511u);                            \
        gi[3] = (int)(__float_as_uint(m3) & 511u);                            \
        gi[4] = (int)(__float_as_uint(m4) & 511u);                            \
        gi[5] = (int)(__float_as_uint(m5) & 511u);                            \
        _Pragma("unroll") for (int j = 0; j < 6; ++j)                         \
            dd[j] = ref_d(X1, Y1, Z1, SS, wvec[gi[j]]);                       \
        _Pragma("unroll") for (int pp = 0; pp < 3; ++pp)                      \
            _Pragma("unroll") for (int i = 4; i >= pp; --i)                   \
                CAS(dd[i], gi[i], dd[i + 1], gi[i + 1]);                      \
        const float EPS32 = 1e-8f;                                            \
        float r0 = __fdiv_rn(1.0f, __fadd_rn(dd[0], EPS32));                  \
        float r1 = __fdiv_rn(1.0f, __fadd_rn(dd[1], EPS32));                  \
        float r2 = __fdiv_rn(1.0f, __fadd_rn(dd[2], EPS32));                  \
        float rs = __fadd_rn(__fadd_rn(r0, r1), r2);                          \
        float w0 = __fdiv_rn(r0, rs);                                         \
        float w1 = __fdiv_rn(r1, rs);                                         \
        float w2 = __fdiv_rn(r2, rs);                                         \
        float interp = __fadd_rn(__fadd_rn(__fmul_rn(f[gi[0]], w0),           \
                                           __fmul_rn(f[gi[1]], w1)),          \
                                 __fmul_rn(f[gi[2]], w2));                    \
        float th = tanhf(interp);                                             \
        out[((size_t)b << 16) | (uint32_t)(NOUT)] =                           \
            __fmul_rn(__fadd_rn(th, 1.0f), 0.5f);                             \
    }

__global__ __launch_bounds__(256, 4) void knn3_kernel(const float* __restrict__ xyz1,
                                                      const float* __restrict__ points2,
                                                      const float4* __restrict__ ws,
                                                      float* __restrict__ out) {
    __shared__ float4 tile[S];          // 8 KB candidate table
    __shared__ float keys_sh[10][256];  // 10 KB per-query key exchange
    const int tid = threadIdx.x;
    const int lane = tid & 63;
    const int wid = tid >> 6;
    const int pr = wid >> 1;            // wave pair (0,1) within block
    const int b = blockIdx.x >> 8;      // 256 blocks per batch
    // pair covers 128 queries: slot0 = lane, slot1 = lane+64
    const int n0 = ((blockIdx.x & 255) << 8) + (pr << 7) + lane;
    const int n1 = n0 + 64;

    const int h_u = __builtin_amdgcn_readfirstlane(wid & 1);  // candidate half
    const float4* __restrict__ wvec = ws + (size_t)b * S;

    tile[tid] = wvec[tid];
    tile[tid + 256] = wvec[tid + 256];
    __syncthreads();

    // two queries per lane (coalesced scalar loads)
    const float* q = xyz1 + (size_t)b * 3 * N;
    float xA = q[n0], yA = q[n0 + N], zA = q[n0 + 2 * N];
    float xB = q[n1], yB = q[n1 + N], zB = q[n1 + 2 * N];
    float ssA = __fadd_rn(__fadd_rn(__fmul_rn(xA, xA), __fmul_rn(yA, yA)),
                          __fmul_rn(zA, zA));
    float ssB = __fadd_rn(__fadd_rn(__fmul_rn(xB, xB), __fmul_rn(yB, yB)),
                          __fmul_rn(zB, zB));
    float cA = ssA + 0.25f, cB = ssB + 0.25f;  // screen-only bias (keys > 0)
    float nxA = -2.0f * xA, nyA = -2.0f * yA, nzA = -2.0f * zA;
    float nxB = -2.0f * xB, nyB = -2.0f * yB, nzB = -2.0f * zB;

    // ---- Phase A: scan own 32 groups from LDS; 5 best (min|gid) per query ----
    float a0 = 3.0e38f, a1 = 3.0e38f, a2 = 3.0e38f, a3 = 3.0e38f, a4 = 3.0e38f;
    float b0 = 3.0e38f, b1 = 3.0e38f, b2 = 3.0e38f, b3 = 3.0e38f, b4 = 3.0e38f;
    const int gid0 = h_u << 5;
#pragma unroll 2
    for (int g = 0; g < 32; ++g) {
        const int gid = gid0 + g;
        float4 p[8];
#pragma unroll
        for (int j = 0; j < 8; ++j) p[j] = tile[gid * 8 + j];  // broadcast b128
        PROC_GQ(nxA, nyA, nzA, cA, a0, a1, a2, a3, a4, gid);
        PROC_GQ(nxB, nyB, nzB, cB, b0, b1, b2, b3, b4, gid);
    }

    // ---- publish both per-query lists; merge within the wave pair ----
    keys_sh[0][tid] = a0; keys_sh[1][tid] = a1; keys_sh[2][tid] = a2;
    keys_sh[3][tid] = a3; keys_sh[4][tid] = a4;
    keys_sh[5][tid] = b0; keys_sh[6][tid] = b1; keys_sh[7][tid] = b2;
    keys_sh[8][tid] = b3; keys_sh[9][tid] = b4;
    __syncthreads();

    const int ptid = tid ^ 64;  // partner wave, same lane
    const float* f = points2 + (size_t)b * S;  // D = 1

    if (h_u == 0) {
        // wave 0 finishes query slot 0: own a-list + partner's a-list
        float p0 = keys_sh[0][ptid], p1 = keys_sh[1][ptid], p2 = keys_sh[2][ptid],
              p3 = keys_sh[3][ptid], p4 = keys_sh[4][ptid];
        INS5L(a0, a1, a2, a3, a4, p0); INS5L(a0, a1, a2, a3, a4, p1);
        INS5L(a0, a1, a2, a3, a4, p2); INS5L(a0, a1, a2, a3, a4, p3);
        INS5L(a0, a1, a2, a3, a4, p4);
        PHASE_C(nxA, nyA, nzA, cA, xA, yA, zA, ssA, a0, a1, a2, a3, a4, n0);
    } else {
        // wave 1 finishes query slot 1: own b-list + partner's b-list
        float p0 = keys_sh[5][ptid], p1 = keys_sh[6][ptid], p2 = keys_sh[7][ptid],
              p3 = keys_sh[8][ptid], p4 = keys_sh[9][ptid];
        INS5L(b0, b1, b2, b3, b4, p0); INS5L(b0, b1, b2, b3, b4, p1);
        INS5L(b0, b1, b2, b3, b4, p2); INS5L(b0, b1, b2, b3, b4, p3);
        INS5L(b0, b1, b2, b3, b4, p4);
        PHASE_C(nxB, nyB, nzB, cB, xB, yB, zB, ssB, b0, b1, b2, b3, b4, n1);
    }
}

extern "C" void kernel_launch(void* const* d_in, const int* in_sizes, int n_in,
                              void* d_out, int out_size, void* d_ws, size_t ws_size,
                              hipStream_t stream) {
    const float* xyz1 = (const float*)d_in[0];
    const float* xyz2 = (const float*)d_in[1];
    const float* points2 = (const float*)d_in[2];
    float* out = (float*)d_out;
    float4* ws = (float4*)d_ws;  // B*S*16 = 32 KB

    prep_kernel<<<(B * S + 255) / 256, 256, 0, stream>>>(xyz2, ws);
    // 1024 blocks x 256 threads: each block covers 256 queries
    // (2 wave pairs x 64 lanes x Q=2), candidates split across the pair
    knn3_kernel<<<(B * N) / 256, 256, 0, stream>>>(xyz1, points2, ws, out);
}